// Round 11
// baseline (105.905 us; speedup 1.0000x reference)
//
#include <hip/hip_runtime.h>

#define NPTS 4096
#define NB   8

typedef __attribute__((ext_vector_type(8)))  short bf16x8;
typedef __attribute__((ext_vector_type(16))) float f32x16;

__device__ __forceinline__ unsigned short bf16_rne(float f) {
    unsigned u = __float_as_uint(f);
    u += 0x7FFFu + ((u >> 16) & 1u);
    return (unsigned short)(u >> 16);
}
__device__ __forceinline__ float bf16_f(unsigned short s) {
    return __uint_as_float(((unsigned)s) << 16);
}

// s(i,j) = ah.bh(3) + al.bh(3) + ah.bl(3) + 1*hh + 1*hl  (11 K-slots of K=16)
// A slots: [ah0,ah1,ah2, al0,al1,al2, ah0,ah1 | ah2, 1, 1, 0,0,0,0,0]
// B slots: [bh0,bh1,bh2, bh0,bh1,bh2, bl0,bl1 | bl2, hh, hl, 0,0,0,0,0]
// (verified on-HW R7/R9/R10: absmax ~0)

// ---------------- pass 0: B fragments only (2 MB) ----------------
__global__ __launch_bounds__(256) void prep_b(
    const float* __restrict__ x, const float* __restrict__ y,
    unsigned short* __restrict__ Bform)
{
    int i   = blockIdx.x * 256 + threadIdx.x;   // 0..65535
    int cid = i >> 12;                          // 0..7: x[b], 8..15: y[b]
    int p   = i & 4095;
    const float* src = (cid < 8) ? x + ((size_t)cid * NPTS + p) * 3
                                 : y + ((size_t)(cid - 8) * NPTS + p) * 3;
    float c0 = src[0], c1 = src[1], c2 = src[2];
    float h  = -0.5f * (c0 * c0 + c1 * c1 + c2 * c2);

    unsigned short h0 = bf16_rne(c0), h1 = bf16_rne(c1), h2 = bf16_rne(c2);
    unsigned short l0 = bf16_rne(c0 - bf16_f(h0));
    unsigned short l1 = bf16_rne(c1 - bf16_f(h1));
    unsigned short l2 = bf16_rne(c2 - bf16_f(h2));
    unsigned short hh = bf16_rne(h);
    unsigned short hl = bf16_rne(h - bf16_f(hh));

    bf16x8 blo, bhi;
    blo[0]=(short)h0; blo[1]=(short)h1; blo[2]=(short)h2; blo[3]=(short)h0;
    blo[4]=(short)h1; blo[5]=(short)h2; blo[6]=(short)l0; blo[7]=(short)l1;
    bhi[0]=(short)l2; bhi[1]=(short)hh; bhi[2]=(short)hl; bhi[3]=0;
    bhi[4]=0; bhi[5]=0; bhi[6]=0; bhi[7]=0;

    int u = p >> 5, pos = p & 31;
    size_t base = ((size_t)cid << 17) + (size_t)u * 1024 + (size_t)pos * 16;
    *(bf16x8*)((char*)Bform + base)       = blo;
    *(bf16x8*)((char*)Bform + base + 512) = bhi;
}

// ---------------- pass 1: fused MFMA chamfer + full reduction ----------------
// grid = 16 clouds * 32 i-chunks = 512 blocks of 256 thr (2 blocks/CU).
// Wave w owns i-tile (iblk*4+w): 32 rows vs ALL 4096 j -> row max completes
// in-block; epilogue folds straight into the scalar loss (1 atomicAdd/wave).
__global__ __launch_bounds__(256, 2) void chamfer_main(
    const float* __restrict__ x, const float* __restrict__ y,
    const unsigned short* __restrict__ Bform,
    float* __restrict__ out)
{
    __shared__ float buf[4][32 * 33];   // 16.9 KB, per-wave regions

    const int bid  = blockIdx.x;
    const int dirb = bid >> 5;        // 0..15 (A-cloud id)
    const int iblk = bid & 31;        // 0..31 (128 rows each)

    const int tid = threadIdx.x;
    const int w   = tid >> 6;         // wave 0..3
    const int l   = tid & 63;
    const int g   = l >> 5;           // k-half
    const int pos = l & 31;           // row/col within tile

    const float* Araw = (dirb < 8) ? x + (size_t)dirb * NPTS * 3
                                   : y + (size_t)(dirb - 8) * NPTS * 3;

    // ---- A fragment in-register from raw floats ----
    bf16x8 afr;
    {
        const float* ap = Araw + (size_t)(iblk * 128 + w * 32 + pos) * 3;
        float c0 = ap[0], c1 = ap[1], c2 = ap[2];
        unsigned short h0 = bf16_rne(c0), h1 = bf16_rne(c1), h2 = bf16_rne(c2);
        unsigned short l0 = bf16_rne(c0 - bf16_f(h0));
        unsigned short l1 = bf16_rne(c1 - bf16_f(h1));
        unsigned short l2 = bf16_rne(c2 - bf16_f(h2));
        const short ONE = (short)0x3F80;
        bf16x8 alo, ahi;
        alo[0]=(short)h0; alo[1]=(short)h1; alo[2]=(short)h2; alo[3]=(short)l0;
        alo[4]=(short)l1; alo[5]=(short)l2; alo[6]=(short)h0; alo[7]=(short)h1;
        ahi[0]=(short)h2; ahi[1]=ONE; ahi[2]=ONE; ahi[3]=0;
        ahi[4]=0; ahi[5]=0; ahi[6]=0; ahi[7]=0;
        #pragma unroll
        for (int e = 0; e < 8; ++e) afr[e] = g ? ahi[e] : alo[e];
    }

    f32x16 zc;
    #pragma unroll
    for (int r = 0; r < 16; ++r) zc[r] = 0.f;

    f32x16 run;
    #pragma unroll
    for (int r = 0; r < 16; ++r) run[r] = -3.0e38f;

    const char* Bbase = (const char*)Bform + ((size_t)(dirb ^ 8) << 17)
                      + (size_t)g * 512 + (size_t)pos * 16;

    // ---- 3-stage pipeline over 128 B tiles, 2 tiles/iter ----
    bf16x8 cb0 = *(const bf16x8*)(Bbase);
    bf16x8 cb1 = *(const bf16x8*)(Bbase + 1024);
    bf16x8 pb0 = *(const bf16x8*)(Bbase + 2048);
    bf16x8 pb1 = *(const bf16x8*)(Bbase + 3072);

    #pragma unroll 1
    for (int j = 0; j < 128; j += 2) {
        int jn = j + 4; if (jn >= 128) jn -= 128;   // harmless wrap reload
        bf16x8 nb0 = *(const bf16x8*)(Bbase + (size_t)jn * 1024);
        bf16x8 nb1 = *(const bf16x8*)(Bbase + (size_t)jn * 1024 + 1024);
        f32x16 d0 = __builtin_amdgcn_mfma_f32_32x32x16_bf16(afr, cb0, zc, 0, 0, 0);
        f32x16 d1 = __builtin_amdgcn_mfma_f32_32x32x16_bf16(afr, cb1, zc, 0, 0, 0);
        #pragma unroll
        for (int r = 0; r < 16; ++r)
            run[r] = fmaxf(fmaxf(d0[r], d1[r]), run[r]);   // v_max3_f32
        cb0 = pb0; cb1 = pb1; pb0 = nb0; pb1 = nb1;
    }

    // ---- epilogue: row max -> loss, all in-block ----
    #pragma unroll
    for (int r = 0; r < 16; ++r) {
        int rowin = (r & 3) + 8 * (r >> 2) + 4 * g;   // verified C/D map
        buf[w][rowin * 33 + pos] = run[r];
    }
    __syncthreads();

    if (l < 32) {
        float m = buf[w][l * 33];
        #pragma unroll
        for (int k = 1; k < 32; ++k) m = fmaxf(m, buf[w][l * 33 + k]);
        // h_a in fp32 from raw
        const float* aq = Araw + (size_t)(iblk * 128 + w * 32 + l) * 3;
        float a0 = aq[0], a1 = aq[1], a2 = aq[2];
        float c  = m - 0.5f * (a0 * a0 + a1 * a1 + a2 * a2);
        // sum across the 32 active lanes (xor targets stay in 0..31)
        #pragma unroll
        for (int mask = 16; mask >= 1; mask >>= 1)
            c += __shfl_xor(c, mask);
        if (l == 0)
            atomicAdd(out, c * (-2.0f * 0.005f / 32768.f));
    }
}

extern "C" void kernel_launch(void* const* d_in, const int* in_sizes, int n_in,
                              void* d_out, int out_size, void* d_ws, size_t ws_size,
                              hipStream_t stream) {
    const float* x = (const float*)d_in[0];
    const float* y = (const float*)d_in[1];
    float* out = (float*)d_out;

    unsigned short* Bform = (unsigned short*)d_ws;   // 2 MB

    hipMemsetAsync(out, 0, sizeof(float), stream);
    prep_b<<<dim3(256), dim3(256), 0, stream>>>(x, y, Bform);
    chamfer_main<<<dim3(512), dim3(256), 0, stream>>>(x, y, Bform, out);
}